// Round 8
// baseline (195.373 us; speedup 1.0000x reference)
//
#include <hip/hip_runtime.h>

typedef unsigned short ushort_t;
typedef __attribute__((ext_vector_type(8))) short bf16x8;
typedef __attribute__((ext_vector_type(4))) short s16x4;
typedef __attribute__((ext_vector_type(4))) float f32x4;
typedef __attribute__((ext_vector_type(16))) float f32x16;

#define BATCH 8
#define SEQ   1024
#define MEMT  8
#define LREAL 1032
#define LPAD  1152   // 9 * 128
#define DMODEL 768
#define NH    12
#define DH    64

// 0.125 * log2(e): Q pre-scaled in GEMM epilogue so attn does exp2(s) directly.
#define CEXP 0.18033688011112042f

__device__ __forceinline__ ushort_t f2b(float x) {
  union { float f; unsigned u; } c; c.f = x;
  unsigned u = c.u;
  unsigned r = (u + 0x7fffu + ((u >> 16) & 1u)) >> 16;
  return (ushort_t)r;
}

#if defined(__has_builtin)
#if __has_builtin(__builtin_amdgcn_global_load_lds)
#define HAVE_GLL 1
#endif
#if __has_builtin(__builtin_amdgcn_exp2f)
#define EXP2F(x) __builtin_amdgcn_exp2f(x)
#endif
#endif
#ifndef EXP2F
#define EXP2F(x) __expf((x) * 0.6931471805599453f)
#endif

// Raw barrier with fine-grained vmcnt (keeps newest DMA prefetches in flight) PLUS
// lgkmcnt(0) so no wave crosses with LDS ops in flight (R6 failure mode).
#define WAITBAR_0 asm volatile("s_waitcnt vmcnt(0) lgkmcnt(0)\n\ts_barrier" ::: "memory")
#define WAITBAR_2 asm volatile("s_waitcnt vmcnt(2) lgkmcnt(0)\n\ts_barrier" ::: "memory")
#define WAITBAR_4 asm volatile("s_waitcnt vmcnt(4) lgkmcnt(0)\n\ts_barrier" ::: "memory")

__device__ __forceinline__ void stage16(const ushort_t* g, ushort_t* lds_wave_base) {
#ifdef HAVE_GLL
  __builtin_amdgcn_global_load_lds(
      (const __attribute__((address_space(1))) unsigned int*)g,
      (__attribute__((address_space(3))) unsigned int*)lds_wave_base,
      16, 0, 0);
#else
  int lane = threadIdx.x & 63;
  *(bf16x8*)(lds_wave_base + lane * 8) = *(const bf16x8*)g;
#endif
}

// Merged prep: blocks [0,6912) build Xm; [6912,8640) cast weights.
__global__ __launch_bounds__(256) void prep(const float* __restrict__ hidden,
                                            const float* __restrict__ memv,
                                            const float* __restrict__ Wq,
                                            const float* __restrict__ Wk,
                                            const float* __restrict__ Wv,
                                            ushort_t* __restrict__ Xm,
                                            ushort_t* __restrict__ Wqb,
                                            ushort_t* __restrict__ Wkb,
                                            ushort_t* __restrict__ Wvb) {
  int bx = blockIdx.x;
  if (bx < 6912) {
    unsigned idx = ((unsigned)bx * 256u + threadIdx.x) * 4u;
    const unsigned perB = (unsigned)LPAD * DMODEL;
    unsigned b = idx / perB;
    unsigned rem = idx - b * perB;
    unsigned row = rem / DMODEL;
    unsigned col = rem - row * DMODEL;
    f32x4 v;
    if (row < SEQ) {
      v = *(const f32x4*)(hidden + ((size_t)b * SEQ + row) * DMODEL + col);
    } else if (row < LREAL) {
      v = *(const f32x4*)(memv + (size_t)(row - SEQ) * DMODEL + col);
    } else {
      v = (f32x4){0.f, 0.f, 0.f, 0.f};
    }
    s16x4 p;
    p[0] = (short)f2b(v[0]); p[1] = (short)f2b(v[1]);
    p[2] = (short)f2b(v[2]); p[3] = (short)f2b(v[3]);
    *(s16x4*)(Xm + idx) = p;
  } else {
    int t = bx - 6912;
    int m = t / 576;
    int i = (t - m * 576) * 256 + threadIdx.x;
    const float* src = m == 0 ? Wq : (m == 1 ? Wk : Wv);
    ushort_t* dst = m == 0 ? Wqb : (m == 1 ? Wkb : Wvb);
    f32x4 v = *(const f32x4*)(src + (size_t)i * 4);
    s16x4 p;
    p[0] = (short)f2b(v[0]); p[1] = (short)f2b(v[1]);
    p[2] = (short)f2b(v[2]); p[3] = (short)f2b(v[3]);
    *(s16x4*)(dst + (size_t)i * 4) = p;
  }
}

// Fused QKV projection, 32x32x16 MFMA version.
// 256 threads, 4 waves 2x2, each wave 64x64 out (4 x f32x16 acc). BK=32, triple-buffered
// vmcnt pipeline. LDS fragment reads XOR-swizzled at 16B-chunk granularity (swizzle
// applied to the GLOBAL source address so global_load_lds' lane*16 layout still works):
// LDS chunk p of row r holds global chunk p^(r&3) -> frag reads are 2-lanes/bank (free).
__global__ __launch_bounds__(256, 3) void gemm_fused(
    const ushort_t* __restrict__ Xm,
    const ushort_t* __restrict__ Wqb, const ushort_t* __restrict__ Wkb,
    const ushort_t* __restrict__ Wvb,
    const float* __restrict__ bq, const float* __restrict__ bk,
    const float* __restrict__ bv,
    ushort_t* __restrict__ Qb, ushort_t* __restrict__ Kb,
    ushort_t* __restrict__ Vtb) {
  // 3 bufs @ i*8192 ushorts (16 KB): As @ +0 (128x32), Bs @ +4096.
  // Epilogue image 128x136 (34.8 KB) aliases the buffers.
  __shared__ __align__(16) ushort_t S[24576];

  const int tid = threadIdx.x;
  const int wave = tid >> 6, lane = tid & 63;
  const int wm = wave >> 1, wn = wave & 1;
  const int m0 = lane & 31;          // fragment row/col within 32-group
  const int lh = lane >> 5;          // k-half selector
  const int sw = lane & 3;           // read-side swizzle key (= row&3 of frag row)
  const int lrow4 = lane >> 2;       // staging row within 16-row chunk
  const int scol = (((lane & 3) ^ ((lane >> 2) & 3)) << 3);  // swizzled source col

  // ---- XCD-pinned decode (1248 blocks, same as prior rounds) ----
  int bx = blockIdx.x;
  int task, xt, yt, b;
  if (bx < 432) {
    int slot = bx & 7, rest = bx >> 3;
    int y = rest % 6, vhi = rest / 6;
    int v = slot + 8 * vhi;
    task = 2; xt = v % 9; b = v / 9; yt = y;
  } else if (bx < 816) {
    int t = bx - 432;
    int slot = t & 7, rest = t >> 3;
    int x = rest % 6, qhi = rest / 6;
    int q = slot + 8 * qhi;
    task = 0; xt = x; yt = q & 7; b = q >> 3;
  } else {
    int t = bx - 816;
    int slot = t & 7, rest = t >> 3;
    int x = rest % 6, khi = rest / 6;
    int k = slot + 8 * khi;
    task = 1; xt = x; yt = k % 9; b = k / 9;
  }
  const int rowTile = yt * 128, colTile = xt * 128;
  const ushort_t* Xb = Xm + (size_t)b * LPAD * DMODEL;
  const ushort_t* A = task == 2 ? Wvb : Xb;
  const ushort_t* W = task == 2 ? Xb : (task == 0 ? Wqb : Wkb);
  const float* bias = task == 2 ? bv : (task == 0 ? bq : bk);

  // staging: 16 chunks of 1 KB (8 A + 8 B); wave w stages A{w,w+4}, B{w,w+4}.
  const ushort_t* Ar0 = A + (size_t)(rowTile + wave * 16 + lrow4) * DMODEL + scol;
  const ushort_t* Ar1 = A + (size_t)(rowTile + (wave + 4) * 16 + lrow4) * DMODEL + scol;
  const ushort_t* Br0 = W + (size_t)(colTile + wave * 16 + lrow4) * DMODEL + scol;
  const ushort_t* Br1 = W + (size_t)(colTile + (wave + 4) * 16 + lrow4) * DMODEL + scol;

#define STAGE_T(k0_, buf_)                                   \
  {                                                          \
    stage16(Ar0 + (k0_), (buf_) + wave * 512);               \
    stage16(Ar1 + (k0_), (buf_) + (wave + 4) * 512);         \
    stage16(Br0 + (k0_), (buf_) + 4096 + wave * 512);        \
    stage16(Br1 + (k0_), (buf_) + 4096 + (wave + 4) * 512);  \
  }

  f32x16 acc[2][2];
#pragma unroll
  for (int mt = 0; mt < 2; ++mt)
#pragma unroll
    for (int nt = 0; nt < 2; ++nt)
#pragma unroll
      for (int r = 0; r < 16; ++r) acc[mt][nt][r] = 0.f;

  auto compute = [&](const ushort_t* cur) {
    bf16x8 af[2][2], bfr[2][2];
#pragma unroll
    for (int ks = 0; ks < 2; ++ks) {
      int chunk = ((ks * 2 + lh) ^ sw) * 8;   // swizzled 16B-chunk offset (ushorts)
#pragma unroll
      for (int mt = 0; mt < 2; ++mt)
        af[mt][ks] = *(const bf16x8*)&cur[(wm * 64 + mt * 32 + m0) * 32 + chunk];
#pragma unroll
      for (int nt = 0; nt < 2; ++nt)
        bfr[nt][ks] = *(const bf16x8*)&cur[4096 + (wn * 64 + nt * 32 + m0) * 32 + chunk];
    }
#pragma unroll
    for (int ks = 0; ks < 2; ++ks)
#pragma unroll
      for (int mt = 0; mt < 2; ++mt)
#pragma unroll
        for (int nt = 0; nt < 2; ++nt)
          acc[mt][nt] = __builtin_amdgcn_mfma_f32_32x32x16_bf16(
              af[mt][ks], bfr[nt][ks], acc[mt][nt], 0, 0, 0);
  };

  // prologue: tiles 0,1 in flight (8 loads/wave outstanding)
  STAGE_T(0, S)
  STAGE_T(32, S + 8192)

  for (int i = 0; i < 22; ++i) {
    WAITBAR_4;                      // tile i landed; tile i+1 (4 loads) still in flight
    STAGE_T((i + 2) * 32, S + ((i + 2) % 3) * 8192)
    compute(S + (i % 3) * 8192);
  }
  WAITBAR_4; compute(S + 8192);     // i=22, 22%3=1
  WAITBAR_0; compute(S + 16384);    // i=23, 23%3=2

  // ---- epilogue: acc -> LDS bf16 image (stride 136) -> coalesced dwordx4 stores ----
  __syncthreads();
  const float scale = task == 0 ? CEXP : 1.0f;
#pragma unroll
  for (int mt = 0; mt < 2; ++mt)
#pragma unroll
    for (int nt = 0; nt < 2; ++nt) {
      int lc = wn * 64 + nt * 32 + m0;
      float bcol = (task == 2) ? 0.f : bias[colTile + lc];
#pragma unroll
      for (int r = 0; r < 16; ++r) {
        int lr = wm * 64 + mt * 32 + (r & 3) + ((r >> 2) << 3) + (lh << 2);
        float bsv = (task == 2) ? bias[rowTile + lr] : bcol;
        S[lr * 136 + lc] = f2b((acc[mt][nt][r] + bsv) * scale);
      }
    }
  __syncthreads();

#pragma unroll
  for (int half = 0; half < 2; ++half) {
    int t = tid + half * 256;
    int row = t >> 2;
    int segu = (t & 3) * 32;
    bf16x8 v0 = *(const bf16x8*)&S[row * 136 + segu + 0];
    bf16x8 v1 = *(const bf16x8*)&S[row * 136 + segu + 8];
    bf16x8 v2 = *(const bf16x8*)&S[row * 136 + segu + 16];
    bf16x8 v3 = *(const bf16x8*)&S[row * 136 + segu + 24];
    if (task == 2) {
      int d = rowTile + row;
      ushort_t* gp = Vtb + (((size_t)b * NH + (d >> 6)) * DH + (d & 63)) * LPAD + colTile + segu;
      *(bf16x8*)(gp + 0) = v0;  *(bf16x8*)(gp + 8) = v1;
      *(bf16x8*)(gp + 16) = v2; *(bf16x8*)(gp + 24) = v3;
    } else {
      ushort_t* out = task == 0 ? Qb : Kb;
      const int Rows = task == 0 ? SEQ : LPAD;
      int colbase = colTile + segu;
      int h = colbase >> 6, dd = colbase & 63;
      ushort_t* gp = out + (((size_t)b * NH + h) * Rows + rowTile + row) * DH + dd;
      *(bf16x8*)(gp + 0) = v0;  *(bf16x8*)(gp + 8) = v1;
      *(bf16x8*)(gp + 16) = v2; *(bf16x8*)(gp + 24) = v3;
    }
  }
}

// Attention: triple-buffered 64-key tiles, raw-barrier vmcnt pipeline (unchanged from R7).
__global__ __launch_bounds__(256, 2) void attn(const ushort_t* __restrict__ Q,
                                               const ushort_t* __restrict__ K,
                                               const ushort_t* __restrict__ Vt,
                                               float* __restrict__ Out) {
  __shared__ __align__(16) ushort_t KV[24576];
  __shared__ __align__(16) ushort_t Ps[8192];   // per wave 2048: [kc][row32][col32]

  const int tid = threadIdx.x, wave = tid >> 6, lane = tid & 63;
  const int quad = lane >> 4, l15 = lane & 15;
  const int lrow4 = lane >> 2, lcol8 = (lane & 3) << 3;
  const int bh = blockIdx.x, qt = blockIdx.y;
  const int h = bh % NH, b = bh / NH;

  const ushort_t* Qp = Q + (((size_t)b * NH + h) * SEQ + qt * 128) * DH;
  const ushort_t* Kp = K + ((size_t)b * NH + h) * LPAD * DH;
  const ushort_t* Vp = Vt + ((size_t)b * NH + h) * DH * LPAD;
  ushort_t* Pw = Ps + wave * 2048;

  bf16x8 qf[2][2];
#pragma unroll
  for (int mt = 0; mt < 2; ++mt)
#pragma unroll
    for (int kk = 0; kk < 2; ++kk)
      qf[mt][kk] = *(const bf16x8*)&Qp[(wave * 32 + mt * 16 + l15) * DH + kk * 32 + quad * 8];

  bf16x8 ones8;
#pragma unroll
  for (int j = 0; j < 8; ++j) ones8[j] = (short)0x3f80;

  f32x4 ob[2][4] = {};
  f32x4 obl[2] = {};

#define STAGE_KV(key0_, buf_)                                                        \
  {                                                                                  \
    _Pragma("unroll")                                                                \
    for (int s = 0; s < 2; ++s) {                                                    \
      int c = wave + s * 4;                                                          \
      int hi = c >> 2, lo = c & 3;                                                   \
      stage16(Kp + (size_t)((key0_) + lo * 16 + lrow4) * DH + hi * 32 + lcol8,       \
              (buf_) + c * 512);                                                     \
      stage16(Vp + (size_t)(lo * 16 + lrow4) * LPAD + (key0_) + hi * 32 + lcol8,     \
              (buf_) + 4096 + c * 512);                                              \
    }                                                                                \
  }

  auto computeAttn = [&](int kt, const ushort_t* cur) {
    f32x4 sc[2][4] = {};
#pragma unroll
    for (int kk = 0; kk < 2; ++kk)
#pragma unroll
      for (int nt = 0; nt < 4; ++nt) {
        bf16x8 kf = *(const bf16x8*)&cur[kk * 2048 + (nt * 16 + l15) * 32 + quad * 8];
#pragma unroll
        for (int mt = 0; mt < 2; ++mt)
          sc[mt][nt] = __builtin_amdgcn_mfma_f32_16x16x32_bf16(qf[mt][kk], kf, sc[mt][nt], 0, 0, 0);
      }

    if (kt < 16) {
#pragma unroll
      for (int mt = 0; mt < 2; ++mt)
#pragma unroll
        for (int nt = 0; nt < 4; ++nt)
#pragma unroll
          for (int r = 0; r < 4; ++r) {
            union { float f; unsigned u; } cu;
            cu.f = EXP2F(sc[mt][nt][r]);
            Pw[(nt >> 1) * 1024 + (mt * 16 + quad * 4 + r) * 32 + (nt & 1) * 16 + l15] =
                (ushort_t)(cu.u >> 16);
          }
    } else {
      bool valid0 = (l15 < 8);
#pragma unroll
      for (int mt = 0; mt < 2; ++mt)
#pragma unroll
        for (int nt = 0; nt < 4; ++nt) {
          bool valid = (nt == 0) && valid0;
#pragma unroll
          for (int r = 0; r < 4; ++r) {
            union { float f; unsigned u; } cu;
            cu.f = valid ? EXP2F(sc[mt][nt][r]) : 0.f;
            Pw[(nt >> 1) * 1024 + (mt * 16 + quad * 4 + r) * 32 + (nt & 1) * 16 + l15] =
                (ushort_t)(cu.u >> 16);
          }
        }
    }

#pragma unroll
    for (int kc = 0; kc < 2; ++kc) {
      bf16x8 pf[2];
#pragma unroll
      for (int mt = 0; mt < 2; ++mt)
        pf[mt] = *(const bf16x8*)&Pw[kc * 1024 + (mt * 16 + l15) * 32 + quad * 8];
#pragma unroll
      for (int dt = 0; dt < 4; ++dt) {
        bf16x8 vf = *(const bf16x8*)&cur[4096 + kc * 2048 + (dt * 16 + l15) * 32 + quad * 8];
#pragma unroll
        for (int mt = 0; mt < 2; ++mt)
          ob[mt][dt] = __builtin_amdgcn_mfma_f32_16x16x32_bf16(pf[mt], vf, ob[mt][dt], 0, 0, 0);
      }
#pragma unroll
      for (int mt = 0; mt < 2; ++mt)
        obl[mt] = __builtin_amdgcn_mfma_f32_16x16x32_bf16(pf[mt], ones8, obl[mt], 0, 0, 0);
    }
  };

  STAGE_KV(0, KV)
  STAGE_KV(64, KV + 8192)

  for (int kt = 0; kt < 15; ++kt) {
    WAITBAR_4;
    STAGE_KV((kt + 2) * 64, KV + ((kt + 2) % 3) * 8192)
    computeAttn(kt, KV + (kt % 3) * 8192);
  }
  WAITBAR_4; computeAttn(15, KV);            // 15%3 = 0
  WAITBAR_0; computeAttn(16, KV + 8192);     // 16%3 = 1

#pragma unroll
  for (int mt = 0; mt < 2; ++mt) {
    int row0 = qt * 128 + wave * 32 + mt * 16 + quad * 4;
    f32x4 linv;
#pragma unroll
    for (int r = 0; r < 4; ++r) linv[r] = 1.0f / obl[mt][r];
#pragma unroll
    for (int dt = 0; dt < 4; ++dt) {
      int col = h * DH + dt * 16 + l15;
#pragma unroll
      for (int r = 0; r < 4; ++r)
        Out[((size_t)b * SEQ + row0 + r) * DMODEL + col] = ob[mt][dt][r] * linv[r];
    }
  }
}

extern "C" void kernel_launch(void* const* d_in, const int* in_sizes, int n_in,
                              void* d_out, int out_size, void* d_ws, size_t ws_size,
                              hipStream_t stream) {
  const float* hidden = (const float*)d_in[0];
  const float* memv   = (const float*)d_in[1];
  const float* Wq = (const float*)d_in[2];
  const float* bq = (const float*)d_in[3];
  const float* Wk = (const float*)d_in[4];
  const float* bk = (const float*)d_in[5];
  const float* Wv = (const float*)d_in[6];
  const float* bv = (const float*)d_in[7];
  float* out = (float*)d_out;

  char* ws = (char*)d_ws;
  size_t off = 0;
  ushort_t* Xm  = (ushort_t*)(ws + off); off += (size_t)BATCH * LPAD * DMODEL * 2;
  ushort_t* Wqb = (ushort_t*)(ws + off); off += (size_t)DMODEL * DMODEL * 2;
  ushort_t* Wkb = (ushort_t*)(ws + off); off += (size_t)DMODEL * DMODEL * 2;
  ushort_t* Wvb = (ushort_t*)(ws + off); off += (size_t)DMODEL * DMODEL * 2;
  ushort_t* Qb  = (ushort_t*)(ws + off); off += (size_t)BATCH * NH * SEQ * DH * 2;
  ushort_t* Kb  = (ushort_t*)(ws + off); off += (size_t)BATCH * NH * LPAD * DH * 2;
  ushort_t* Vtb = (ushort_t*)(ws + off);

  prep<<<dim3(8640), 256, 0, stream>>>(hidden, memv, Wq, Wk, Wv, Xm, Wqb, Wkb, Wvb);
  gemm_fused<<<dim3(1248), 256, 0, stream>>>(Xm, Wqb, Wkb, Wvb, bq, bk, bv, Qb, Kb, Vtb);
  attn<<<dim3(96, 8), 256, 0, stream>>>(Qb, Kb, Vtb, out);
}